// Round 1
// baseline (563.871 us; speedup 1.0000x reference)
//
#include <hip/hip_runtime.h>
#include <math.h>

typedef unsigned short u16;
typedef __attribute__((ext_vector_type(8))) short bf16x8;
typedef __attribute__((ext_vector_type(4))) float f32x4;
typedef __attribute__((ext_vector_type(4))) int i32x4;
typedef __attribute__((ext_vector_type(4))) short s16x4;
typedef __attribute__((ext_vector_type(4))) unsigned short u16x4;

#define MFMA16(a,b,c) __builtin_amdgcn_mfma_f32_16x16x32_bf16((a),(b),(c),0,0,0)

__device__ __forceinline__ u16 f2bf(float x){
  unsigned int u = __float_as_uint(x);
  u += 0x7fffu + ((u >> 16) & 1u);   // RNE
  return (u16)(u >> 16);
}

// ---------------------------------------------------------------------------
// prep: fp32 -> bf16 conversions + weight transposes into B-operand layout
// Wt[n][k] = W[k][n]. grid = 4096 x 256 (exactly 1,048,576 threads)
// ---------------------------------------------------------------------------
__global__ __launch_bounds__(256) void prep(
    const float* __restrict__ nodes, const float* __restrict__ q1, const float* __restrict__ lastn,
    const float* __restrict__ Wqf, const float* __restrict__ Wql, const float* __restrict__ Wk,
    const float* __restrict__ Wv, const float* __restrict__ Wc,
    u16* __restrict__ nodesb, u16* __restrict__ q1b, u16* __restrict__ lastb,
    u16* __restrict__ WtKV, u16* __restrict__ WtQF, u16* __restrict__ WtQL, u16* __restrict__ WtC)
{
  const int tid = blockIdx.x * 256 + threadIdx.x;
  const int NT = 1048576;
  // nodes: 16,777,216 elems = 4,194,304 float4, 4 per thread
  for (int i = tid; i < 4194304; i += NT) {
    float4 v = ((const float4*)nodes)[i];
    u16x4 o; o[0]=f2bf(v.x); o[1]=f2bf(v.y); o[2]=f2bf(v.z); o[3]=f2bf(v.w);
    *(u16x4*)&nodesb[i*4] = o;
  }
  { // q1 / last: 1,048,576 float4 each = exactly one per thread
    float4 v = ((const float4*)q1)[tid];
    u16x4 o; o[0]=f2bf(v.x); o[1]=f2bf(v.y); o[2]=f2bf(v.z); o[3]=f2bf(v.w);
    *(u16x4*)&q1b[tid*4] = o;
    v = ((const float4*)lastn)[tid];
    o[0]=f2bf(v.x); o[1]=f2bf(v.y); o[2]=f2bf(v.z); o[3]=f2bf(v.w);
    *(u16x4*)&lastb[tid*4] = o;
  }
  if (tid < 262144) {
    int n = tid >> 9, k = tid & 511;
    WtQF[tid] = f2bf(Wqf[k*512 + n]);
    WtQL[tid] = f2bf(Wql[k*512 + n]);
    WtC[tid]  = f2bf(Wc[k*512 + n]);
  }
  if (tid < 524288) { // WtKV[n][k]: n<512 -> Wk col n, else Wv col n-512
    int n = tid >> 9, k = tid & 511;
    WtKV[tid] = f2bf(n < 512 ? Wk[k*512 + n] : Wv[k*512 + (n-512)]);
  }
}

// ---------------------------------------------------------------------------
// K|V projection GEMM: A = nodes_bf16 [32768,512], B = WtKV [1024][512].
// Epilogue scatters K[b,h,m,d] and V transposed Vt[b,h,d,m].
// grid = 2048 (256 m-blocks x 8 n-blocks), 256 thr, 128x128 tile, BK=32.
// ---------------------------------------------------------------------------
__global__ __launch_bounds__(256) void gemm_kv(const u16* __restrict__ A, const u16* __restrict__ Bw,
                                               u16* __restrict__ Kout, u16* __restrict__ Vout)
{
  const int mb = blockIdx.x & 255, nb = blockIdx.x >> 8;
  const int t = threadIdx.x, w = t >> 6, l = t & 63, q = l >> 4, ln = l & 15;
  const int wm = (w >> 1) * 64, wn = (w & 1) * 64;
  __shared__ u16 As[128*32];
  __shared__ u16 Bs[128*32];
  f32x4 acc[4][4];
  #pragma unroll
  for (int i=0;i<4;i++)
    #pragma unroll
    for (int j=0;j<4;j++)
      #pragma unroll
      for (int r=0;r<4;r++) acc[i][j][r] = 0.f;
  const int m0 = mb*128, n0 = nb*128;
  for (int kc = 0; kc < 16; kc++) {
    __syncthreads();
    #pragma unroll
    for (int c=0;c<2;c++) {
      int chunk = t + 256*c;
      int row = chunk >> 2, kk = (chunk & 3) * 8;
      *(i32x4*)&As[row*32+kk] = *(const i32x4*)&A[(m0+row)*512 + kc*32 + kk];
      *(i32x4*)&Bs[row*32+kk] = *(const i32x4*)&Bw[(n0+row)*512 + kc*32 + kk];
    }
    __syncthreads();
    bf16x8 af[4], bfr[4];
    #pragma unroll
    for (int i=0;i<4;i++) af[i] = *(bf16x8*)&As[(wm + i*16 + ln)*32 + q*8];
    #pragma unroll
    for (int j=0;j<4;j++) bfr[j] = *(bf16x8*)&Bs[(wn + j*16 + ln)*32 + q*8];
    #pragma unroll
    for (int i=0;i<4;i++)
      #pragma unroll
      for (int j=0;j<4;j++)
        acc[i][j] = MFMA16(af[i], bfr[j], acc[i][j]);
  }
  const int bb = m0 >> 10;
  #pragma unroll
  for (int i=0;i<4;i++) {
    int gm = m0 + wm + i*16 + q*4;
    int m = gm & 1023;
    #pragma unroll
    for (int j=0;j<4;j++) {
      int gn = n0 + wn + j*16 + ln;
      if (gn < 512) {
        int h = gn >> 5, d = gn & 31;
        u16* kp = Kout + ((bb*16 + h)*1024 + m)*32 + d;
        #pragma unroll
        for (int r=0;r<4;r++) kp[r*32] = f2bf(acc[i][j][r]);
      } else {
        int n2 = gn - 512, h = n2 >> 5, d = n2 & 31;
        u16* vp = Vout + ((bb*16 + h)*32 + d)*1024 + m;
        s16x4 o;
        #pragma unroll
        for (int r=0;r<4;r++) o[r] = (short)f2bf(acc[i][j][r]);
        *(s16x4*)vp = o;
      }
    }
  }
}

// ---------------------------------------------------------------------------
// Q projection: Q = q1@Wqf + last@Wql. M=8192, N=512, K=512+512.
// grid = 256 (64 m x 4 n). Output Q[b,h,pomo,d].
// ---------------------------------------------------------------------------
__global__ __launch_bounds__(256) void gemm_q(const u16* __restrict__ A1, const u16* __restrict__ A2,
                                              const u16* __restrict__ B1, const u16* __restrict__ B2,
                                              u16* __restrict__ Qout)
{
  const int mb = blockIdx.x & 63, nb = blockIdx.x >> 6;
  const int t = threadIdx.x, w = t >> 6, l = t & 63, q = l >> 4, ln = l & 15;
  const int wm = (w >> 1) * 64, wn = (w & 1) * 64;
  __shared__ u16 As[128*32];
  __shared__ u16 Bs[128*32];
  f32x4 acc[4][4];
  #pragma unroll
  for (int i=0;i<4;i++)
    #pragma unroll
    for (int j=0;j<4;j++)
      #pragma unroll
      for (int r=0;r<4;r++) acc[i][j][r] = 0.f;
  const int m0 = mb*128, n0 = nb*128;
  for (int kc = 0; kc < 32; kc++) {
    const u16* Ap = (kc < 16) ? A1 : A2;
    const u16* Bp = (kc < 16) ? B1 : B2;
    const int k0 = (kc & 15) * 32;
    __syncthreads();
    #pragma unroll
    for (int c=0;c<2;c++) {
      int chunk = t + 256*c;
      int row = chunk >> 2, kk = (chunk & 3) * 8;
      *(i32x4*)&As[row*32+kk] = *(const i32x4*)&Ap[(m0+row)*512 + k0 + kk];
      *(i32x4*)&Bs[row*32+kk] = *(const i32x4*)&Bp[(n0+row)*512 + k0 + kk];
    }
    __syncthreads();
    bf16x8 af[4], bfr[4];
    #pragma unroll
    for (int i=0;i<4;i++) af[i] = *(bf16x8*)&As[(wm + i*16 + ln)*32 + q*8];
    #pragma unroll
    for (int j=0;j<4;j++) bfr[j] = *(bf16x8*)&Bs[(wn + j*16 + ln)*32 + q*8];
    #pragma unroll
    for (int i=0;i<4;i++)
      #pragma unroll
      for (int j=0;j<4;j++)
        acc[i][j] = MFMA16(af[i], bfr[j], acc[i][j]);
  }
  #pragma unroll
  for (int i=0;i<4;i++) {
    int gm = m0 + wm + i*16 + q*4;
    int bb = gm >> 8, pm = gm & 255;
    #pragma unroll
    for (int j=0;j<4;j++) {
      int gn = n0 + wn + j*16 + ln;
      int h = gn >> 5, d = gn & 31;
      u16* qp = Qout + ((bb*16 + h)*256 + pm)*32 + d;
      #pragma unroll
      for (int r=0;r<4;r++) qp[r*32] = f2bf(acc[i][j][r]);
    }
  }
}

// ---------------------------------------------------------------------------
// Fused attention per (b, h, pomo-tile of 64). grid = 2048, 256 thr (4 waves).
// Single-pass softmax (no max subtraction; logits are tiny / exp(-inf)=0).
// ---------------------------------------------------------------------------
__global__ __launch_bounds__(256) void attn(const u16* __restrict__ Qg, const u16* __restrict__ Kg,
                                            const u16* __restrict__ Vtg, const float* __restrict__ mask,
                                            u16* __restrict__ Og)
{
  const int bid = blockIdx.x;
  const int pt = bid & 3, h = (bid >> 2) & 15, bb = bid >> 6;
  const int t = threadIdx.x, w = t >> 6, l = t & 63, q = l >> 4, ln = l & 15;
  __shared__ u16 Qs[64*32];    // [pomo][d]
  __shared__ u16 Ks[128*32];   // [m][d]
  __shared__ u16 Vs[32*136];   // [d][m] padded (+8) to break bank conflicts
  __shared__ u16 Ps[64*136];   // [pomo][m] padded, wave-private rows
  const int qbase = ((bb*16 + h)*256 + pt*64)*32;
  *(i32x4*)&Qs[t*8] = *(const i32x4*)&Qg[qbase + t*8];
  const int kbase = (bb*16 + h)*1024*32;
  const int vbase = (bb*16 + h)*32*1024;
  float rs[4] = {0.f,0.f,0.f,0.f};
  f32x4 oacc[2];
  #pragma unroll
  for (int dt=0;dt<2;dt++)
    #pragma unroll
    for (int r=0;r<4;r++) oacc[dt][r] = 0.f;
  __syncthreads();
  const bf16x8 aq = *(bf16x8*)&Qs[(w*16 + ln)*32 + q*8];
  const float scale = 0.17677669529663687f;  // 1/sqrt(32)
  const int prow_g = bb*256 + pt*64 + w*16 + q*4;
  for (int mc = 0; mc < 8; mc++) {
    __syncthreads();
    #pragma unroll
    for (int c=0;c<2;c++) {
      int chunk = t + 256*c;
      int krow = chunk >> 2, kk = (chunk & 3) * 8;
      *(i32x4*)&Ks[krow*32+kk] = *(const i32x4*)&Kg[kbase + (mc*128+krow)*32 + kk];
      int vrow = chunk >> 4, vc = chunk & 15;
      *(i32x4*)&Vs[vrow*136 + vc*8] = *(const i32x4*)&Vtg[vbase + vrow*1024 + mc*128 + vc*8];
    }
    __syncthreads();
    #pragma unroll
    for (int j=0;j<8;j++) {
      bf16x8 bk = *(bf16x8*)&Ks[(j*16 + ln)*32 + q*8];
      f32x4 z;
      #pragma unroll
      for (int r=0;r<4;r++) z[r] = 0.f;
      f32x4 s = MFMA16(aq, bk, z);
      const float* mp = mask + prow_g*1024 + mc*128 + j*16 + ln;
      #pragma unroll
      for (int r=0;r<4;r++) {
        float e = __expf(s[r]*scale + mp[r*1024]);
        rs[r] += e;
        Ps[(w*16 + q*4 + r)*136 + j*16 + ln] = f2bf(e);
      }
    }
    // PV: Ps rows are wave-private -> no barrier needed
    #pragma unroll
    for (int kc=0;kc<4;kc++) {
      bf16x8 ap = *(bf16x8*)&Ps[(w*16 + ln)*136 + kc*32 + q*8];
      #pragma unroll
      for (int dt=0;dt<2;dt++) {
        bf16x8 bv = *(bf16x8*)&Vs[(dt*16 + ln)*136 + kc*32 + q*8];
        oacc[dt] = MFMA16(ap, bv, oacc[dt]);
      }
    }
  }
  #pragma unroll
  for (int r=0;r<4;r++) {
    float v = rs[r];
    v += __shfl_xor(v,1); v += __shfl_xor(v,2); v += __shfl_xor(v,4); v += __shfl_xor(v,8);
    rs[r] = 1.0f / v;
  }
  const int orow = bb*256 + pt*64 + w*16 + q*4;
  #pragma unroll
  for (int dt=0;dt<2;dt++)
    #pragma unroll
    for (int r=0;r<4;r++)
      Og[(orow + r)*512 + h*32 + dt*16 + ln] = f2bf(oacc[dt][r]*rs[r]);
}

// ---------------------------------------------------------------------------
// Combine GEMM: mh = out_concat @ Wc + bias. M=8192,N=512,K=512. grid=256.
// ---------------------------------------------------------------------------
__global__ __launch_bounds__(256) void gemm_cmb(const u16* __restrict__ A, const u16* __restrict__ Bw,
                                                const float* __restrict__ bias, u16* __restrict__ Mout)
{
  const int mb = blockIdx.x & 63, nb = blockIdx.x >> 6;
  const int t = threadIdx.x, w = t >> 6, l = t & 63, q = l >> 4, ln = l & 15;
  const int wm = (w >> 1) * 64, wn = (w & 1) * 64;
  __shared__ u16 As[128*32];
  __shared__ u16 Bs[128*32];
  f32x4 acc[4][4];
  #pragma unroll
  for (int i=0;i<4;i++)
    #pragma unroll
    for (int j=0;j<4;j++)
      #pragma unroll
      for (int r=0;r<4;r++) acc[i][j][r] = 0.f;
  const int m0 = mb*128, n0 = nb*128;
  for (int kc = 0; kc < 16; kc++) {
    __syncthreads();
    #pragma unroll
    for (int c=0;c<2;c++) {
      int chunk = t + 256*c;
      int row = chunk >> 2, kk = (chunk & 3) * 8;
      *(i32x4*)&As[row*32+kk] = *(const i32x4*)&A[(m0+row)*512 + kc*32 + kk];
      *(i32x4*)&Bs[row*32+kk] = *(const i32x4*)&Bw[(n0+row)*512 + kc*32 + kk];
    }
    __syncthreads();
    bf16x8 af[4], bfr[4];
    #pragma unroll
    for (int i=0;i<4;i++) af[i] = *(bf16x8*)&As[(wm + i*16 + ln)*32 + q*8];
    #pragma unroll
    for (int j=0;j<4;j++) bfr[j] = *(bf16x8*)&Bs[(wn + j*16 + ln)*32 + q*8];
    #pragma unroll
    for (int i=0;i<4;i++)
      #pragma unroll
      for (int j=0;j<4;j++)
        acc[i][j] = MFMA16(af[i], bfr[j], acc[i][j]);
  }
  #pragma unroll
  for (int i=0;i<4;i++) {
    int gmb = m0 + wm + i*16 + q*4;
    #pragma unroll
    for (int j=0;j<4;j++) {
      int gn = n0 + wn + j*16 + ln;
      float bv = bias[gn];
      #pragma unroll
      for (int r=0;r<4;r++) Mout[(gmb + r)*512 + gn] = f2bf(acc[i][j][r] + bv);
    }
  }
}

// ---------------------------------------------------------------------------
// final1: score2 = mh @ nodes^T / sqrt(512); logit = 10*tanh + mask; exp to
// d_out (unnormalized) + per-row sums to ws. grid = 256 (32 b x 8 pomo-tiles
// of 32). nodes B-fragments read straight from global (L2-resident per b).
// ---------------------------------------------------------------------------
__global__ __launch_bounds__(256) void final1(const u16* __restrict__ mhb, const u16* __restrict__ nodesb,
                                              const float* __restrict__ mask, float* __restrict__ outE,
                                              float* __restrict__ rowsum)
{
  const int bid = blockIdx.x;
  const int pt = bid & 7, bb = bid >> 3;
  const int t = threadIdx.x, w = t >> 6, l = t & 63, q = l >> 4, ln = l & 15;
  const int wrow = w & 1, wcol = w >> 1;
  __shared__ u16 As[32*520];      // mh tile [32][512] padded +8
  __shared__ float rsL[4][16];
  const int abase = (bb*256 + pt*32)*512;
  #pragma unroll
  for (int c=0;c<8;c++) {
    int chunk = t + 256*c;
    int row = chunk >> 6, kk = (chunk & 63) * 8;
    *(i32x4*)&As[row*520 + kk] = *(const i32x4*)&mhb[abase + row*512 + kk];
  }
  __syncthreads();
  float rloc[4] = {0.f,0.f,0.f,0.f};
  const int nbase = bb*1024*512;
  const float inv_se = 0.044194173824159216f;  // 1/sqrt(512)
  for (int nc = 0; nc < 8; nc++) {
    f32x4 acc[4];
    #pragma unroll
    for (int ct=0;ct<4;ct++)
      #pragma unroll
      for (int r=0;r<4;r++) acc[ct][r] = 0.f;
    #pragma unroll 2
    for (int kc=0;kc<16;kc++) {
      bf16x8 af = *(bf16x8*)&As[(wrow*16 + ln)*520 + kc*32 + q*8];
      #pragma unroll
      for (int ct=0;ct<4;ct++) {
        int col = nc*128 + wcol*64 + ct*16 + ln;
        bf16x8 bfr = *(const bf16x8*)&nodesb[nbase + col*512 + kc*32 + q*8];
        acc[ct] = MFMA16(af, bfr, acc[ct]);
      }
    }
    const int prow = bb*256 + pt*32 + wrow*16 + q*4;
    #pragma unroll
    for (int ct=0;ct<4;ct++) {
      int col = nc*128 + wcol*64 + ct*16 + ln;
      const float* mp = mask + prow*1024 + col;
      float* op = outE + prow*1024 + col;
      #pragma unroll
      for (int r=0;r<4;r++) {
        float s = acc[ct][r] * inv_se;
        s = fminf(fmaxf(s, -15.f), 15.f);
        float e2 = __expf(2.f*s);
        float lg = 10.f*(e2 - 1.f)/(e2 + 1.f) + mp[r*1024];
        float e = __expf(lg);
        rloc[r] += e;
        op[r*1024] = e;
      }
    }
  }
  #pragma unroll
  for (int r=0;r<4;r++) {
    float v = rloc[r];
    v += __shfl_xor(v,1); v += __shfl_xor(v,2); v += __shfl_xor(v,4); v += __shfl_xor(v,8);
    rloc[r] = v;
  }
  if (ln == 0) {
    #pragma unroll
    for (int r=0;r<4;r++) rsL[w][q*4 + r] = rloc[r];
  }
  __syncthreads();
  if (t < 32) {
    float v = rsL[t >> 4][t & 15] + rsL[2 + (t >> 4)][t & 15];
    rowsum[bb*256 + pt*32 + t] = v;
  }
}

// normalize: probs = exp / rowsum. grid = 8192 x 256, one float4 each.
__global__ __launch_bounds__(256) void final2(float* __restrict__ out, const float* __restrict__ rowsum)
{
  int i = blockIdx.x*256 + threadIdx.x;   // float4 index, 2,097,152 total
  float4 v = ((const float4*)out)[i];
  float inv = 1.0f / rowsum[i >> 8];
  v.x *= inv; v.y *= inv; v.z *= inv; v.w *= inv;
  ((float4*)out)[i] = v;
}

extern "C" void kernel_launch(void* const* d_in, const int* in_sizes, int n_in,
                              void* d_out, int out_size, void* d_ws, size_t ws_size,
                              hipStream_t stream)
{
  (void)in_sizes; (void)n_in; (void)out_size; (void)ws_size;
  const float* nodes = (const float*)d_in[0];
  const float* q1    = (const float*)d_in[1];
  const float* lastn = (const float*)d_in[2];
  const float* mask  = (const float*)d_in[3];
  const float* Wqf   = (const float*)d_in[4];
  const float* Wql   = (const float*)d_in[5];
  const float* Wk    = (const float*)d_in[6];
  const float* Wv    = (const float*)d_in[7];
  const float* Wc    = (const float*)d_in[8];
  const float* bias  = (const float*)d_in[9];
  float* out = (float*)d_out;

  char* p = (char*)d_ws;
  u16* nodesb = (u16*)p; p += 33554432;   // [32][1024][512] bf16
  u16* q1b    = (u16*)p; p += 8388608;    // [32][256][512]
  u16* lastb  = (u16*)p; p += 8388608;
  u16* WtKV   = (u16*)p; p += 1048576;    // [1024][512]
  u16* WtQF   = (u16*)p; p += 524288;
  u16* WtQL   = (u16*)p; p += 524288;
  u16* WtC    = (u16*)p; p += 524288;
  u16* Kt     = (u16*)p; p += 33554432;   // K [32][16][1024][32]
  u16* Vt     = (u16*)p; p += 33554432;   // V^T [32][16][32][1024]
  u16* Qh     = (u16*)p; p += 8388608;    // Q [32][16][256][32]
  u16* oc     = (u16*)p; p += 8388608;    // out_concat [32][256][512]
  u16* mhb    = (u16*)p; p += 8388608;    // mh [32][256][512]
  float* rsum = (float*)p; p += 32768;    // [8192]

  prep<<<4096, 256, 0, stream>>>(nodes, q1, lastn, Wqf, Wql, Wk, Wv, Wc,
                                 nodesb, q1b, lastb, WtKV, WtQF, WtQL, WtC);
  gemm_kv<<<2048, 256, 0, stream>>>(nodesb, WtKV, Kt, Vt);
  gemm_q<<<256, 256, 0, stream>>>(q1b, lastb, WtQF, WtQL, Qh);
  attn<<<2048, 256, 0, stream>>>(Qh, Kt, Vt, mask, oc);
  gemm_cmb<<<256, 256, 0, stream>>>(oc, WtC, bias, mhb);
  final1<<<256, 256, 0, stream>>>(mhb, nodesb, mask, out, rsum);
  final2<<<8192, 256, 0, stream>>>(out, rsum);
}

// Round 2
// 458.597 us; speedup vs baseline: 1.2296x; 1.2296x over previous
//
#include <hip/hip_runtime.h>
#include <math.h>

typedef unsigned short u16;
typedef __attribute__((ext_vector_type(8))) short bf16x8;
typedef __attribute__((ext_vector_type(4))) float f32x4;
typedef __attribute__((ext_vector_type(4))) int i32x4;
typedef __attribute__((ext_vector_type(4))) short s16x4;
typedef __attribute__((ext_vector_type(4))) unsigned short u16x4;

#define MFMA16(a,b,c) __builtin_amdgcn_mfma_f32_16x16x32_bf16((a),(b),(c),0,0,0)

__device__ __forceinline__ u16 f2bf(float x){
  unsigned int u = __float_as_uint(x);
  u += 0x7fffu + ((u >> 16) & 1u);   // RNE
  return (u16)(u >> 16);
}
__device__ __forceinline__ float bf2f(u16 x){
  return __uint_as_float(((unsigned)x) << 16);
}
// async global->LDS, 16B per lane. LDS image must be lane-linear.
__device__ __forceinline__ void gload16(const void* g, void* l){
  __builtin_amdgcn_global_load_lds((const __attribute__((address_space(1))) void*)g,
                                   (__attribute__((address_space(3))) void*)l, 16, 0, 0);
}

// ---------------------------------------------------------------------------
// prep: fp32->bf16 + weight transposes + maskP packing.
// maskP[b][rt(16)][col(1024)][p(16)] bf16, p = row-in-16 (MFMA C-layout order).
// grid = 4096 x 256.
// ---------------------------------------------------------------------------
__global__ __launch_bounds__(256) void prep(
    const float* __restrict__ nodes, const float* __restrict__ q1, const float* __restrict__ lastn,
    const float* __restrict__ mask,
    const float* __restrict__ Wqf, const float* __restrict__ Wql, const float* __restrict__ Wk,
    const float* __restrict__ Wv, const float* __restrict__ Wc,
    u16* __restrict__ nodesb, u16* __restrict__ q1b, u16* __restrict__ lastb,
    u16* __restrict__ WtKV, u16* __restrict__ WtQF, u16* __restrict__ WtQL, u16* __restrict__ WtC,
    u16* __restrict__ maskP)
{
  const int tid = blockIdx.x * 256 + threadIdx.x;
  const int NT = 1048576;
  for (int i = tid; i < 4194304; i += NT) {
    float4 v = ((const float4*)nodes)[i];
    u16x4 o; o[0]=f2bf(v.x); o[1]=f2bf(v.y); o[2]=f2bf(v.z); o[3]=f2bf(v.w);
    *(u16x4*)&nodesb[i*4] = o;
  }
  {
    float4 v = ((const float4*)q1)[tid];
    u16x4 o; o[0]=f2bf(v.x); o[1]=f2bf(v.y); o[2]=f2bf(v.z); o[3]=f2bf(v.w);
    *(u16x4*)&q1b[tid*4] = o;
    v = ((const float4*)lastn)[tid];
    o[0]=f2bf(v.x); o[1]=f2bf(v.y); o[2]=f2bf(v.z); o[3]=f2bf(v.w);
    *(u16x4*)&lastb[tid*4] = o;
  }
  if (tid < 262144) {
    int n = tid >> 9, k = tid & 511;
    WtQF[tid] = f2bf(Wqf[k*512 + n]);
    WtQL[tid] = f2bf(Wql[k*512 + n]);
    WtC[tid]  = f2bf(Wc[k*512 + n]);
  }
  if (tid < 524288) {
    int n = tid >> 9, k = tid & 511;
    WtKV[tid] = f2bf(n < 512 ? Wk[k*512 + n] : Wv[k*512 + (n-512)]);
  }
  if (tid < 524288) {  // maskP: tid = (b*16 + rt)*1024 + c
    int brt = tid >> 10, c = tid & 1023;
    const float* mp = mask + (brt*16)*1024 + c;   // brt*16 = b*256 + rt*16
    u16 vals[16];
    #pragma unroll
    for (int p=0;p<16;p++) vals[p] = f2bf(mp[p*1024]);
    *(i32x4*)&maskP[tid*16]     = *(i32x4*)&vals[0];
    *(i32x4*)&maskP[tid*16 + 8] = *(i32x4*)&vals[8];
  }
}

// ---------------------------------------------------------------------------
// K|V projection GEMM, 128x128 tile, fragment-ordered LDS + global_load_lds.
// grid = 2048 (256 m x 8 n).
// ---------------------------------------------------------------------------
__global__ __launch_bounds__(256) void gemm_kv(const u16* __restrict__ A, const u16* __restrict__ Bw,
                                               u16* __restrict__ Kout, u16* __restrict__ Vout)
{
  const int mb = blockIdx.x & 255, nb = blockIdx.x >> 8;
  const int t = threadIdx.x, w = t >> 6, l = t & 63, q = l >> 4, ln = l & 15;
  const int wm = (w >> 1) * 64, wn = (w & 1) * 64;
  __shared__ u16 As[4096];   // [qk(4)][row(128)][8]
  __shared__ u16 Bs[4096];
  f32x4 acc[4][4];
  #pragma unroll
  for (int i=0;i<4;i++)
    #pragma unroll
    for (int j=0;j<4;j++)
      #pragma unroll
      for (int r=0;r<4;r++) acc[i][j][r] = 0.f;
  const int m0 = mb*128, n0 = nb*128;
  const int row = t & 127, qk0 = t >> 7;
  for (int kc = 0; kc < 16; kc++) {
    __syncthreads();
    #pragma unroll
    for (int c=0;c<2;c++) {
      int qk = qk0 + 2*c, chunk = t + 256*c;
      gload16(&A[(m0+row)*512 + kc*32 + qk*8], &As[chunk*8]);
      gload16(&Bw[(n0+row)*512 + kc*32 + qk*8], &Bs[chunk*8]);
    }
    __syncthreads();
    bf16x8 af[4], bfr[4];
    #pragma unroll
    for (int i=0;i<4;i++) af[i] = *(bf16x8*)&As[(q*128 + wm + i*16 + ln)*8];
    #pragma unroll
    for (int j=0;j<4;j++) bfr[j] = *(bf16x8*)&Bs[(q*128 + wn + j*16 + ln)*8];
    #pragma unroll
    for (int i=0;i<4;i++)
      #pragma unroll
      for (int j=0;j<4;j++)
        acc[i][j] = MFMA16(af[i], bfr[j], acc[i][j]);
  }
  const int bb = m0 >> 10;
  #pragma unroll
  for (int i=0;i<4;i++) {
    int gm = m0 + wm + i*16 + q*4;
    int m = gm & 1023;
    #pragma unroll
    for (int j=0;j<4;j++) {
      int gn = n0 + wn + j*16 + ln;
      if (gn < 512) {
        int h = gn >> 5, d = gn & 31;
        u16* kp = Kout + ((bb*16 + h)*1024 + m)*32 + d;
        #pragma unroll
        for (int r=0;r<4;r++) kp[r*32] = f2bf(acc[i][j][r]);
      } else {
        int n2 = gn - 512, h = n2 >> 5, d = n2 & 31;
        u16* vp = Vout + ((bb*16 + h)*32 + d)*1024 + m;
        s16x4 o;
        #pragma unroll
        for (int r=0;r<4;r++) o[r] = (short)f2bf(acc[i][j][r]);
        *(s16x4*)vp = o;
      }
    }
  }
}

// ---------------------------------------------------------------------------
// Q projection, 64x64 tile, Q = (q1@Wqf + last@Wql) * (1/sqrt(32)).
// grid = 1024 (128 m x 8 n).
// ---------------------------------------------------------------------------
__global__ __launch_bounds__(256) void gemm_q(const u16* __restrict__ A1, const u16* __restrict__ A2,
                                              const u16* __restrict__ B1, const u16* __restrict__ B2,
                                              u16* __restrict__ Qout)
{
  const int mb = blockIdx.x >> 3, nb = blockIdx.x & 7;
  const int t = threadIdx.x, w = t >> 6, l = t & 63, q = l >> 4, ln = l & 15;
  const int wm = (w >> 1) * 32, wn = (w & 1) * 32;
  __shared__ u16 As[2048];   // [qk(4)][row(64)][8]
  __shared__ u16 Bs[2048];
  f32x4 acc[2][2];
  #pragma unroll
  for (int i=0;i<2;i++)
    #pragma unroll
    for (int j=0;j<2;j++)
      #pragma unroll
      for (int r=0;r<4;r++) acc[i][j][r] = 0.f;
  const int m0 = mb*64, n0 = nb*64;
  const int row = t & 63, qk = t >> 6;
  for (int kc = 0; kc < 32; kc++) {
    const u16* Ap = (kc < 16) ? A1 : A2;
    const u16* Bp = (kc < 16) ? B1 : B2;
    const int k0 = (kc & 15) * 32;
    __syncthreads();
    gload16(&Ap[(m0+row)*512 + k0 + qk*8], &As[t*8]);
    gload16(&Bp[(n0+row)*512 + k0 + qk*8], &Bs[t*8]);
    __syncthreads();
    bf16x8 af[2], bfr[2];
    #pragma unroll
    for (int i=0;i<2;i++) af[i] = *(bf16x8*)&As[(q*64 + wm + i*16 + ln)*8];
    #pragma unroll
    for (int j=0;j<2;j++) bfr[j] = *(bf16x8*)&Bs[(q*64 + wn + j*16 + ln)*8];
    #pragma unroll
    for (int i=0;i<2;i++)
      #pragma unroll
      for (int j=0;j<2;j++)
        acc[i][j] = MFMA16(af[i], bfr[j], acc[i][j]);
  }
  const float sc = 0.17677669529663687f;
  #pragma unroll
  for (int i=0;i<2;i++) {
    int gm = m0 + wm + i*16 + q*4;
    int bb = gm >> 8, pm = gm & 255;
    #pragma unroll
    for (int j=0;j<2;j++) {
      int gn = n0 + wn + j*16 + ln;
      int h = gn >> 5, d = gn & 31;
      u16* qp = Qout + ((bb*16 + h)*256 + pm)*32 + d;
      #pragma unroll
      for (int r=0;r<4;r++) qp[r*32] = f2bf(acc[i][j][r]*sc);
    }
  }
}

// ---------------------------------------------------------------------------
// Fused attention per (b, h, pomo64). grid = 2048, 4 waves.
// Chunked P (wave-private [16][40] LDS), packed bf16 mask, lds-direct staging.
// ---------------------------------------------------------------------------
__global__ __launch_bounds__(256) void attn(const u16* __restrict__ Qg, const u16* __restrict__ Kg,
                                            const u16* __restrict__ Vtg, const u16* __restrict__ maskP,
                                            u16* __restrict__ Og)
{
  const int bid = blockIdx.x;
  const int pt = bid & 3, h = (bid >> 2) & 15, bb = bid >> 6;
  const int t = threadIdx.x, w = t >> 6, l = t & 63, q = l >> 4, ln = l & 15;
  __shared__ u16 Qs[2048];     // [qk(4)][row(64)][8]
  __shared__ u16 Ks[4096];     // [qk(4)][m(128)][8]
  __shared__ u16 Vs[4096];     // [moct(16)][d(32)][8]
  __shared__ u16 Ps[4*640];    // per wave [16][40]
  u16* Pw = &Ps[w*640];
  const int qbase = ((bb*16 + h)*256 + pt*64)*32;
  gload16(&Qg[qbase + (t & 63)*32 + (t >> 6)*8], &Qs[t*8]);
  const int kbase = (bb*16 + h)*1024*32;
  const int vbase = (bb*16 + h)*32*1024;
  float rs[4] = {0.f,0.f,0.f,0.f};
  f32x4 oacc[2];
  #pragma unroll
  for (int dt=0;dt<2;dt++)
    #pragma unroll
    for (int r=0;r<4;r++) oacc[dt][r] = 0.f;
  __syncthreads();
  const bf16x8 aq = *(bf16x8*)&Qs[(q*64 + w*16 + ln)*8];
  const u16* mrow = maskP + (bb*16 + pt*4 + w)*16384 + q*4;
  for (int mc = 0; mc < 8; mc++) {
    __syncthreads();
    // K: chunk = moct-free [qk][m] linear; V: [moct][d] linear
    gload16(&Kg[kbase + (mc*128 + (t & 127))*32 + (t >> 7)*8],       &Ks[t*8]);
    gload16(&Kg[kbase + (mc*128 + (t & 127))*32 + ((t >> 7)+2)*8],   &Ks[(t+256)*8]);
    gload16(&Vtg[vbase + (t & 31)*1024 + mc*128 + (t >> 5)*8],       &Vs[t*8]);
    gload16(&Vtg[vbase + (t & 31)*1024 + mc*128 + ((t >> 5)+8)*8],   &Vs[(t+256)*8]);
    u16x4 mq[8];
    #pragma unroll
    for (int j2=0;j2<8;j2++)
      mq[j2] = *(const u16x4*)&mrow[(mc*128 + j2*16 + ln)*16];
    __syncthreads();
    #pragma unroll
    for (int ch=0; ch<4; ch++) {
      bf16x8 bk0 = *(bf16x8*)&Ks[(q*128 + (ch*2+0)*16 + ln)*8];
      bf16x8 bk1 = *(bf16x8*)&Ks[(q*128 + (ch*2+1)*16 + ln)*8];
      f32x4 zz = {0.f,0.f,0.f,0.f};
      f32x4 s0 = MFMA16(aq, bk0, zz);
      f32x4 s1 = MFMA16(aq, bk1, zz);
      #pragma unroll
      for (int r=0;r<4;r++) {
        float e0 = __expf(s0[r] + bf2f(mq[ch*2+0][r]));
        float e1 = __expf(s1[r] + bf2f(mq[ch*2+1][r]));
        rs[r] += e0 + e1;
        Pw[(q*4+r)*40 + ln]      = f2bf(e0);
        Pw[(q*4+r)*40 + 16 + ln] = f2bf(e1);
      }
      bf16x8 ap  = *(bf16x8*)&Pw[ln*40 + q*8];
      bf16x8 bv0 = *(bf16x8*)&Vs[((ch*4+q)*32 + ln)*8];
      bf16x8 bv1 = *(bf16x8*)&Vs[((ch*4+q)*32 + 16 + ln)*8];
      oacc[0] = MFMA16(ap, bv0, oacc[0]);
      oacc[1] = MFMA16(ap, bv1, oacc[1]);
    }
  }
  #pragma unroll
  for (int r=0;r<4;r++) {
    float v = rs[r];
    v += __shfl_xor(v,1); v += __shfl_xor(v,2); v += __shfl_xor(v,4); v += __shfl_xor(v,8);
    rs[r] = __builtin_amdgcn_rcpf(v);
  }
  const int orow = bb*256 + pt*64 + w*16 + q*4;
  #pragma unroll
  for (int dt=0;dt<2;dt++)
    #pragma unroll
    for (int r=0;r<4;r++)
      Og[(orow + r)*512 + h*32 + dt*16 + ln] = f2bf(oacc[dt][r]*rs[r]);
}

// ---------------------------------------------------------------------------
// Combine GEMM 64x64: mh = oc @ Wc + bias. grid = 1024.
// ---------------------------------------------------------------------------
__global__ __launch_bounds__(256) void gemm_cmb(const u16* __restrict__ A, const u16* __restrict__ Bw,
                                                const float* __restrict__ bias, u16* __restrict__ Mout)
{
  const int mb = blockIdx.x >> 3, nb = blockIdx.x & 7;
  const int t = threadIdx.x, w = t >> 6, l = t & 63, q = l >> 4, ln = l & 15;
  const int wm = (w >> 1) * 32, wn = (w & 1) * 32;
  __shared__ u16 As[2048];
  __shared__ u16 Bs[2048];
  f32x4 acc[2][2];
  #pragma unroll
  for (int i=0;i<2;i++)
    #pragma unroll
    for (int j=0;j<2;j++)
      #pragma unroll
      for (int r=0;r<4;r++) acc[i][j][r] = 0.f;
  const int m0 = mb*64, n0 = nb*64;
  const int row = t & 63, qk = t >> 6;
  for (int kc = 0; kc < 16; kc++) {
    __syncthreads();
    gload16(&A[(m0+row)*512 + kc*32 + qk*8], &As[t*8]);
    gload16(&Bw[(n0+row)*512 + kc*32 + qk*8], &Bs[t*8]);
    __syncthreads();
    bf16x8 af[2], bfr[2];
    #pragma unroll
    for (int i=0;i<2;i++) af[i] = *(bf16x8*)&As[(q*64 + wm + i*16 + ln)*8];
    #pragma unroll
    for (int j=0;j<2;j++) bfr[j] = *(bf16x8*)&Bs[(q*64 + wn + j*16 + ln)*8];
    #pragma unroll
    for (int i=0;i<2;i++)
      #pragma unroll
      for (int j=0;j<2;j++)
        acc[i][j] = MFMA16(af[i], bfr[j], acc[i][j]);
  }
  #pragma unroll
  for (int i=0;i<2;i++) {
    int gmb = m0 + wm + i*16 + q*4;
    #pragma unroll
    for (int j=0;j<2;j++) {
      int gn = n0 + wn + j*16 + ln;
      float bv = bias[gn];
      #pragma unroll
      for (int r=0;r<4;r++) Mout[(gmb + r)*512 + gn] = f2bf(acc[i][j][r] + bv);
    }
  }
}

// ---------------------------------------------------------------------------
// final1: score2 = mh @ nodes^T / sqrt(512), 10*tanh + mask, exp + rowsum.
// grid = 512 (32 b x 16 row-tiles), 4 waves x 256 cols.
// ---------------------------------------------------------------------------
__global__ __launch_bounds__(256) void final1(const u16* __restrict__ mhb, const u16* __restrict__ nodesb,
                                              const u16* __restrict__ maskP, float* __restrict__ outE,
                                              float* __restrict__ rowsum)
{
  const int bid = blockIdx.x;
  const int rt = bid & 15, bb = bid >> 4;
  const int t = threadIdx.x, w = t >> 6, l = t & 63, q = l >> 4, ln = l & 15;
  __shared__ u16 As[8192];      // [qk(64)][row(16)][8]
  __shared__ float rsL[4][16];
  const int abase = (bb*256 + rt*16)*512;
  #pragma unroll
  for (int c=0;c<4;c++) {
    int chunk = t + 256*c;
    gload16(&mhb[abase + (chunk & 15)*512 + (chunk >> 4)*8], &As[chunk*8]);
  }
  __syncthreads();
  float rloc[4] = {0.f,0.f,0.f,0.f};
  const int nbase = bb*524288;
  f32x4 acc[16];
  #pragma unroll
  for (int ct=0;ct<16;ct++)
    #pragma unroll
    for (int r=0;r<4;r++) acc[ct][r] = 0.f;
  for (int kc=0;kc<16;kc++) {
    bf16x8 af = *(bf16x8*)&As[((kc*4 + q)*16 + ln)*8];
    #pragma unroll
    for (int ct=0;ct<16;ct++) {
      int col = w*256 + ct*16 + ln;
      bf16x8 bfr = *(const bf16x8*)&nodesb[nbase + col*512 + kc*32 + q*8];
      acc[ct] = MFMA16(af, bfr, acc[ct]);
    }
  }
  const float c2 = 0.08838834764831843f;   // 2/sqrt(512)
  const int prow_base = bb*256 + rt*16;
  #pragma unroll
  for (int ct=0;ct<16;ct++) {
    int col0 = w*256 + ct*16 + ln;
    u16x4 mv = *(const u16x4*)&maskP[((bb*16 + rt)*1024 + col0)*16 + q*4];
    #pragma unroll
    for (int r=0;r<4;r++) {
      float x = acc[ct][r] * c2;
      x = fminf(fmaxf(x, -30.f), 30.f);
      float e2 = __expf(x);
      float lg = 10.f*(e2 - 1.f)*__builtin_amdgcn_rcpf(e2 + 1.f) + bf2f(mv[r]);
      float e = __expf(lg);
      rloc[r] += e;
      outE[(prow_base + q*4 + r)*1024 + col0] = e;
    }
  }
  #pragma unroll
  for (int r=0;r<4;r++) {
    float v = rloc[r];
    v += __shfl_xor(v,1); v += __shfl_xor(v,2); v += __shfl_xor(v,4); v += __shfl_xor(v,8);
    rloc[r] = v;
  }
  if (ln == 0) {
    #pragma unroll
    for (int r=0;r<4;r++) rsL[w][q*4 + r] = rloc[r];
  }
  __syncthreads();
  if (t < 16)
    rowsum[prow_base + t] = rsL[0][t] + rsL[1][t] + rsL[2][t] + rsL[3][t];
}

// normalize: probs = exp / rowsum. grid = 8192 x 256.
__global__ __launch_bounds__(256) void final2(float* __restrict__ out, const float* __restrict__ rowsum)
{
  int i = blockIdx.x*256 + threadIdx.x;
  float4 v = ((const float4*)out)[i];
  float inv = __builtin_amdgcn_rcpf(rowsum[i >> 8]);
  v.x *= inv; v.y *= inv; v.z *= inv; v.w *= inv;
  ((float4*)out)[i] = v;
}

extern "C" void kernel_launch(void* const* d_in, const int* in_sizes, int n_in,
                              void* d_out, int out_size, void* d_ws, size_t ws_size,
                              hipStream_t stream)
{
  (void)in_sizes; (void)n_in; (void)out_size; (void)ws_size;
  const float* nodes = (const float*)d_in[0];
  const float* q1    = (const float*)d_in[1];
  const float* lastn = (const float*)d_in[2];
  const float* mask  = (const float*)d_in[3];
  const float* Wqf   = (const float*)d_in[4];
  const float* Wql   = (const float*)d_in[5];
  const float* Wk    = (const float*)d_in[6];
  const float* Wv    = (const float*)d_in[7];
  const float* Wc    = (const float*)d_in[8];
  const float* bias  = (const float*)d_in[9];
  float* out = (float*)d_out;

  char* p = (char*)d_ws;
  u16* nodesb = (u16*)p; p += 33554432;   // [32][1024][512] bf16
  u16* q1b    = (u16*)p; p += 8388608;    // [32][256][512]
  u16* lastb  = (u16*)p; p += 8388608;
  u16* WtKV   = (u16*)p; p += 1048576;    // [1024][512]
  u16* WtQF   = (u16*)p; p += 524288;
  u16* WtQL   = (u16*)p; p += 524288;
  u16* WtC    = (u16*)p; p += 524288;
  u16* Kt     = (u16*)p; p += 33554432;   // K [32][16][1024][32]
  u16* Vt     = (u16*)p; p += 33554432;   // V^T [32][16][32][1024]
  u16* Qh     = (u16*)p; p += 8388608;    // Q(scaled) [32][16][256][32]
  u16* maskP  = (u16*)p; p += 16777216;   // [32][16][1024][16] bf16
  float* rsum = (float*)p; p += 32768;    // [8192]
  u16* oc  = lastb;   // dead after gemm_q
  u16* mhb = q1b;     // dead after gemm_q

  prep<<<4096, 256, 0, stream>>>(nodes, q1, lastn, mask, Wqf, Wql, Wk, Wv, Wc,
                                 nodesb, q1b, lastb, WtKV, WtQF, WtQL, WtC, maskP);
  gemm_kv<<<2048, 256, 0, stream>>>(nodesb, WtKV, Kt, Vt);
  gemm_q<<<1024, 256, 0, stream>>>(q1b, lastb, WtQF, WtQL, Qh);
  attn<<<2048, 256, 0, stream>>>(Qh, Kt, Vt, maskP, oc);
  gemm_cmb<<<1024, 256, 0, stream>>>(oc, WtC, bias, mhb);
  final1<<<512, 256, 0, stream>>>(mhb, nodesb, maskP, out, rsum);
  final2<<<8192, 256, 0, stream>>>(out, rsum);
}